// Round 12
// baseline (83.557 us; speedup 1.0000x reference)
//
#include <hip/hip_runtime.h>

#define BATCH 8
#define ROWS  2048
#define WIDTH 4096
#define COLS  4096
#define KB    1024   // WIDTH/4 gating blocks along k
#define CBV   1024   // COLS/4  float4s per W row
#define ZPART 32     // row-chunks per batch (partials)
#define RCH   64     // ROWS / ZPART
#define NDOT  256    // dot-kernel blocks (z x k-chunk)

typedef float f32x4 __attribute__((ext_vector_type(4)));

// ---------------------------------------------------------------------------
// Fused kernel, 2048 blocks. CONTIGUOUS job split (bid<1024: colsum,
// bid>=1024: gate) so each stream's blocks cover ALL 8 XCD residues —
// the parity split confined each stream to half the XCDs (R11 theory).
//   colsum: part[z][b][k] = sum_{r in chunk z} X[b,r,k]
//   gate:   wg[b, 4kb+j]  = sum_c W[4kb+j, c] * G[b, kb, c/4]
// ---------------------------------------------------------------------------
__global__ __launch_bounds__(256) void fused_kernel(const f32x4* __restrict__ X,
                                                    const f32x4* __restrict__ Wv,
                                                    const f32x4* __restrict__ Gv,
                                                    f32x4* __restrict__ part,
                                                    float* __restrict__ wg) {
    const int t = threadIdx.x;
    if (blockIdx.x < 1024) {
        // ---------------- colsum: strip pattern (proven) --------------------
        const int s  = blockIdx.x;          // [0, 1024)
        const int k4 = (s & 3) * 256 + t;   // [0, 1024)
        const int b  = (s >> 2) & 7;
        const int z  = s >> 5;              // [0, 32)

        const f32x4* p = X + (size_t)(b * ROWS + z * RCH) * (WIDTH / 4) + k4;
        f32x4 a = {0.f, 0.f, 0.f, 0.f};
#pragma unroll 8
        for (int r = 0; r < RCH; ++r) {
            f32x4 v = p[(size_t)r * (WIDTH / 4)];
            a.x += v.x; a.y += v.y; a.z += v.z; a.w += v.w;
        }
        part[((size_t)(z * BATCH + b) << 10) + k4] = a;
    } else {
        // ---------------- gate: one block per kb ----------------------------
        const int kb = blockIdx.x - 1024;   // [0, 1024)
        const int lane = t & 63, wv = t >> 6;

        f32x4 w[4][4];  // [j][m]: W[4kb+j, 4*(4t+m) .. +3]
#pragma unroll
        for (int j = 0; j < 4; ++j)
#pragma unroll
            for (int m = 0; m < 4; ++m)
                w[j][m] = Wv[(size_t)(4 * kb + j) * CBV + 4 * t + m];

        f32x4 g[8];     // G[b, kb, 4t..4t+3]
#pragma unroll
        for (int b = 0; b < 8; ++b)
            g[b] = Gv[((size_t)(b * KB + kb) << 8) + t];

        float w4[4][4];  // 4-col block sums of W
#pragma unroll
        for (int j = 0; j < 4; ++j)
#pragma unroll
            for (int m = 0; m < 4; ++m)
                w4[j][m] = (w[j][m].x + w[j][m].y) + (w[j][m].z + w[j][m].w);

        float acc[8][4];
#pragma unroll
        for (int b = 0; b < 8; ++b)
#pragma unroll
            for (int j = 0; j < 4; ++j)
                acc[b][j] = g[b].x * w4[j][0] + g[b].y * w4[j][1] +
                            g[b].z * w4[j][2] + g[b].w * w4[j][3];

        // reduce 32 accumulators (b,j) across 256 threads (R8/R9 proven form)
        __shared__ float lds[4][32];
#pragma unroll
        for (int v = 0; v < 32; ++v) {
            float x = acc[v >> 2][v & 3];
#pragma unroll
            for (int o = 1; o < 64; o <<= 1) x += __shfl_xor(x, o, 64);
            if (lane == 0) lds[wv][v] = x;
        }
        __syncthreads();
        if (t < 32) {
            float r = (lds[0][t] + lds[1][t]) + (lds[2][t] + lds[3][t]);
            wg[(size_t)(t >> 2) * WIDTH + 4 * kb + (t & 3)] = r;
        }
    }
}

// ---------------------------------------------------------------------------
// F1: 256 blocks — block (z = bid>>3, kc = bid&7) dots a 16 KB slice of
// part[z] against the matching wg slice (wg chunks go L2-hot).
// ---------------------------------------------------------------------------
__global__ __launch_bounds__(256) void dot_kernel(const f32x4* __restrict__ part,
                                                  const f32x4* __restrict__ wgv,
                                                  float* __restrict__ partial) {
    const int z  = blockIdx.x >> 3;  // [0, 32)
    const int kc = blockIdx.x & 7;   // [0, 8)
    const f32x4* pz = part + ((size_t)z * BATCH << 10);

    float acc = 0.f;
#pragma unroll
    for (int rep = 0; rep < 4; ++rep) {
        const int i = (kc << 10) + rep * 256 + threadIdx.x;
        f32x4 a = pz[i], b = wgv[i];
        acc += a.x * b.x + a.y * b.y + a.z * b.z + a.w * b.w;
    }
#pragma unroll
    for (int o = 1; o < 64; o <<= 1) acc += __shfl_xor(acc, o, 64);
    __shared__ float lds[4];
    const int lane = threadIdx.x & 63, wv = threadIdx.x >> 6;
    if (lane == 0) lds[wv] = acc;
    __syncthreads();
    if (threadIdx.x == 0) partial[blockIdx.x] = (lds[0] + lds[1]) + (lds[2] + lds[3]);
}

// ---------------------------------------------------------------------------
// F2: s = sum(partial[0..256)); out[0] = s*s. One 256-thread block.
// ---------------------------------------------------------------------------
__global__ __launch_bounds__(256) void square_kernel(const float* __restrict__ partial,
                                                     float* __restrict__ out) {
    float v = partial[threadIdx.x];
#pragma unroll
    for (int o = 1; o < 64; o <<= 1) v += __shfl_xor(v, o, 64);
    __shared__ float lds[4];
    const int lane = threadIdx.x & 63, wv = threadIdx.x >> 6;
    if (lane == 0) lds[wv] = v;
    __syncthreads();
    if (threadIdx.x == 0) {
        float s = (lds[0] + lds[1]) + (lds[2] + lds[3]);
        out[0] = s * s;
    }
}

extern "C" void kernel_launch(void* const* d_in, const int* in_sizes, int n_in,
                              void* d_out, int out_size, void* d_ws, size_t ws_size,
                              hipStream_t stream) {
    const float* X = (const float*)d_in[0];  // (8, 2048, 4096)
    const float* W = (const float*)d_in[1];  // (4096, 4096)
    const float* G = (const float*)d_in[2];  // (8, 1024, 1024)
    float* out = (float*)d_out;              // scalar

    float* part    = (float*)d_ws;                           // 4 MB, fully rewritten
    float* wg      = part + (size_t)ZPART * BATCH * WIDTH;   // 128 KB, fully rewritten
    float* partial = wg + (size_t)BATCH * WIDTH;             // 256 f32, fully rewritten

    fused_kernel<<<2048, 256, 0, stream>>>((const f32x4*)X, (const f32x4*)W,
                                           (const f32x4*)G, (f32x4*)part, wg);

    dot_kernel<<<NDOT, 256, 0, stream>>>((const f32x4*)part, (const f32x4*)wg, partial);

    square_kernel<<<1, 256, 0, stream>>>(partial, out);
}

// Round 13
// 80.431 us; speedup vs baseline: 1.0389x; 1.0389x over previous
//
#include <hip/hip_runtime.h>

#define BATCH 8
#define ROWS  2048
#define WIDTH 4096
#define COLS  4096
#define KB    1024   // WIDTH/4 gating blocks along k
#define CBV   1024   // COLS/4  float4s per W row
#define RCH   64     // rows per colsum block

typedef float f32x4 __attribute__((ext_vector_type(4)));

// ---------------------------------------------------------------------------
// K1: wg[b, 4kb+j] = sum_c W[4kb+j, c] * G[b, kb, c/4].  One block per kb
// (proven gate kernel, R8/R9 form). 1024 blocks, ~100 MB read, 128 KB write.
// ---------------------------------------------------------------------------
__global__ __launch_bounds__(256) void wg_kernel(const f32x4* __restrict__ Wv,
                                                 const f32x4* __restrict__ Gv,
                                                 float* __restrict__ wg) {
    const int t  = threadIdx.x;
    const int kb = blockIdx.x;          // [0, 1024)
    const int lane = t & 63, wv = t >> 6;

    f32x4 w[4][4];  // [j][m]: W[4kb+j, 4*(4t+m) .. +3]
#pragma unroll
    for (int j = 0; j < 4; ++j)
#pragma unroll
        for (int m = 0; m < 4; ++m)
            w[j][m] = Wv[(size_t)(4 * kb + j) * CBV + 4 * t + m];

    f32x4 g[8];     // G[b, kb, 4t..4t+3]
#pragma unroll
    for (int b = 0; b < 8; ++b)
        g[b] = Gv[((size_t)(b * KB + kb) << 8) + t];

    float w4[4][4];  // 4-col block sums of W
#pragma unroll
    for (int j = 0; j < 4; ++j)
#pragma unroll
        for (int m = 0; m < 4; ++m)
            w4[j][m] = (w[j][m].x + w[j][m].y) + (w[j][m].z + w[j][m].w);

    float acc[8][4];
#pragma unroll
    for (int b = 0; b < 8; ++b)
#pragma unroll
        for (int j = 0; j < 4; ++j)
            acc[b][j] = g[b].x * w4[j][0] + g[b].y * w4[j][1] +
                        g[b].z * w4[j][2] + g[b].w * w4[j][3];

    // reduce 32 accumulators (b,j) across 256 threads (proven form)
    __shared__ float lds[4][32];
#pragma unroll
    for (int v = 0; v < 32; ++v) {
        float x = acc[v >> 2][v & 3];
#pragma unroll
        for (int o = 1; o < 64; o <<= 1) x += __shfl_xor(x, o, 64);
        if (lane == 0) lds[wv][v] = x;
    }
    __syncthreads();
    if (t < 32) {
        float r = (lds[0][t] + lds[1][t]) + (lds[2][t] + lds[3][t]);
        wg[(size_t)(t >> 2) * WIDTH + 4 * kb + (t & 3)] = r;
    }
}

// ---------------------------------------------------------------------------
// K2: colsum with INLINE dot — no part array. Block s accumulates its
// 4 KB k-strip over 64 rows (proven strip loop), then dots the column-sums
// with the matching wg strip (L2-hot) and block-reduces to partial[s].
// 1024 blocks, 268 MB of X + 4 MB of L2-hot wg re-reads.
// ---------------------------------------------------------------------------
__global__ __launch_bounds__(256) void colsum_dot_kernel(const f32x4* __restrict__ X,
                                                         const f32x4* __restrict__ wg4,
                                                         float* __restrict__ partial) {
    const int t  = threadIdx.x;
    const int s  = blockIdx.x;          // [0, 1024)
    const int k4 = (s & 3) * 256 + t;   // [0, 1024)
    const int b  = (s >> 2) & 7;
    const int z  = s >> 5;              // [0, 32)

    const f32x4* p = X + (size_t)(b * ROWS + z * RCH) * (WIDTH / 4) + k4;
    f32x4 a = {0.f, 0.f, 0.f, 0.f};
#pragma unroll 8
    for (int r = 0; r < RCH; ++r) {
        f32x4 v = p[(size_t)r * (WIDTH / 4)];
        a.x += v.x; a.y += v.y; a.z += v.z; a.w += v.w;
    }

    f32x4 wv = wg4[((size_t)b << 10) + k4];  // wg[b, 4k4 .. 4k4+3]
    float d = a.x * wv.x + a.y * wv.y + a.z * wv.z + a.w * wv.w;

#pragma unroll
    for (int o = 1; o < 64; o <<= 1) d += __shfl_xor(d, o, 64);
    __shared__ float lds[4];
    const int lane = t & 63, wvi = t >> 6;
    if (lane == 0) lds[wvi] = d;
    __syncthreads();
    if (t == 0) partial[s] = (lds[0] + lds[1]) + (lds[2] + lds[3]);
}

// ---------------------------------------------------------------------------
// K3: s = sum(partial[0..1024)); out[0] = s*s. One 256-thread block.
// ---------------------------------------------------------------------------
__global__ __launch_bounds__(256) void square_kernel(const f32x4* __restrict__ partial4,
                                                     float* __restrict__ out) {
    f32x4 v = partial4[threadIdx.x];  // 256 f32x4 = 1024 floats
    float acc = (v.x + v.y) + (v.z + v.w);
#pragma unroll
    for (int o = 1; o < 64; o <<= 1) acc += __shfl_xor(acc, o, 64);
    __shared__ float lds[4];
    const int lane = threadIdx.x & 63, wv = threadIdx.x >> 6;
    if (lane == 0) lds[wv] = acc;
    __syncthreads();
    if (threadIdx.x == 0) {
        float s = (lds[0] + lds[1]) + (lds[2] + lds[3]);
        out[0] = s * s;
    }
}

extern "C" void kernel_launch(void* const* d_in, const int* in_sizes, int n_in,
                              void* d_out, int out_size, void* d_ws, size_t ws_size,
                              hipStream_t stream) {
    const float* X = (const float*)d_in[0];  // (8, 2048, 4096)
    const float* W = (const float*)d_in[1];  // (4096, 4096)
    const float* G = (const float*)d_in[2];  // (8, 1024, 1024)
    float* out = (float*)d_out;              // scalar

    float* wg      = (float*)d_ws;                  // 32768 floats, fully rewritten
    float* partial = wg + (size_t)BATCH * WIDTH;    // 1024 floats, fully rewritten

    wg_kernel<<<KB, 256, 0, stream>>>((const f32x4*)W, (const f32x4*)G, wg);

    colsum_dot_kernel<<<1024, 256, 0, stream>>>((const f32x4*)X, (const f32x4*)wg, partial);

    square_kernel<<<1, 256, 0, stream>>>((const f32x4*)partial, out);
}